// Round 7
// baseline (344.463 us; speedup 1.0000x reference)
//
#include <hip/hip_runtime.h>
#include <hip/hip_bf16.h>

#define NN 4096
#define DD 256
#define BB 32
#define TT 256
#define EPS 1e-6f
#define DECAY 0.97f
#define LOG2_DECAY -0.043943348f

typedef __hip_bfloat16 bf16;
typedef short short8 __attribute__((ext_vector_type(8)));
typedef float floatx4 __attribute__((ext_vector_type(4)));

__device__ __forceinline__ float bfu2f(short u) {
    return __uint_as_float(((unsigned)(unsigned short)u) << 16);
}
__device__ __forceinline__ short f2bfu(float v) {
    bf16 t = __float2bfloat16(v);
    return *reinterpret_cast<short*>(&t);
}

// ---------------- block-wide sum over 256 threads ----------------
__device__ __forceinline__ float blk_sum_256(float v, volatile float* s4) {
#pragma unroll
    for (int o = 32; o > 0; o >>= 1) v += __shfl_down(v, o, 64);
    int lane = threadIdx.x & 63, w = threadIdx.x >> 6;
    __syncthreads();
    if (lane == 0) s4[w] = v;
    __syncthreads();
    return s4[0] + s4[1] + s4[2] + s4[3];
}

// async global->LDS, 16B per lane; dest must be wave-uniform base + lane*16
__device__ __forceinline__ void gl16(const bf16* g, void* l) {
    __builtin_amdgcn_global_load_lds((const __attribute__((address_space(1))) void*)g,
                                     (__attribute__((address_space(3))) void*)l, 16, 0, 0);
}

// XOR-swizzled fragment read for BK=64 layouts (128B rows).
__device__ __forceinline__ short8 frag64(const char* matbase, int row, int c) {
    return *(const short8*)(matbase + row * 128 + (((c) ^ (row & 7)) << 4));
}

// ---------------- dtype detector (bf16-packed vs fp32 inputs) ----------------
__global__ void k_detect(const unsigned short* __restrict__ raw, int* __restrict__ flag) {
    __shared__ int cnt[4];
    int tid = threadIdx.x;
    int bad = 0;
    for (int i = tid; i < 8192; i += 256) {
        unsigned int u = raw[2 * i];
        float v = __uint_as_float(u << 16);
        if (!(fabsf(v) < 1e6f)) bad++;
    }
#pragma unroll
    for (int o = 32; o > 0; o >>= 1) bad += __shfl_down(bad, o, 64);
    int lane = tid & 63, w = tid >> 6;
    if (lane == 0) cnt[w] = bad;
    __syncthreads();
    if (tid == 0) flag[0] = (cnt[0] + cnt[1] + cnt[2] + cnt[3] < 32) ? 1 : 0;
}

// ---------------- convert 3 weight matrices to bf16 ----------------
__global__ __launch_bounds__(256) void k_convert3(const void* __restrict__ s0,
                                                  const void* __restrict__ s1,
                                                  const void* __restrict__ s2,
                                                  bf16* __restrict__ d0,
                                                  bf16* __restrict__ d1,
                                                  bf16* __restrict__ d2,
                                                  const int* __restrict__ flag) {
    const int per = NN * DD / 8;
    int i = blockIdx.x * 256 + threadIdx.x;
    int m = i / per, j = i % per;
    const void* s = (m == 0) ? s0 : (m == 1) ? s1 : s2;
    bf16* d = (m == 0) ? d0 : (m == 1) ? d1 : d2;
    if (flag[0]) {
        ((uint4*)d)[j] = ((const uint4*)s)[j];
    } else {
        const float4* f = (const float4*)s;
        float4 a = f[2 * j], b = f[2 * j + 1];
        short8 o;
        float va[8] = {a.x, a.y, a.z, a.w, b.x, b.y, b.z, b.w};
#pragma unroll
        for (int k = 0; k < 8; k++) o[k] = f2bfu(va[k]);
        ((short8*)d)[j] = o;
    }
}

// ---------------- gather embeddings: Vp (raw) and U=LN(row), both bf16 ----------------
__global__ __launch_bounds__(256) void k_gather_ln(const void* __restrict__ emb,
                                                   const int* __restrict__ idx,
                                                   bf16* __restrict__ Vpb,
                                                   bf16* __restrict__ Ub,
                                                   const int* __restrict__ flag) {
    __shared__ float s4[4];
    int r = blockIdx.x, d = threadIdx.x;
    int tok = idx[r];
    long o = (long)tok * DD + d;
    float e = flag[0] ? __bfloat162float(((const bf16*)emb)[o]) : ((const float*)emb)[o];
    Vpb[(long)r * DD + d] = __float2bfloat16(e);
    float m = blk_sum_256(e, s4) * (1.0f / DD);
    float zc = e - m;
    float var = blk_sum_256(zc * zc, s4) * (1.0f / (DD - 1));
    Ub[(long)r * DD + d] = __float2bfloat16(zc / (sqrtf(fmaxf(var, 0.f)) + EPS));
}

// ---------------- per-batch transpose Ub[b][t][d] -> Ut[b][d][t] ----------------
__global__ __launch_bounds__(256) void k_transpose(const bf16* __restrict__ Ub,
                                                   bf16* __restrict__ Ut) {
    __shared__ bf16 tile[32][33];
    int b = blockIdx.z;
    int t0 = blockIdx.x * 32, d0 = blockIdx.y * 32;
    const bf16* src = Ub + (long)b * TT * DD;
    bf16* dst = Ut + (long)b * DD * TT;
    int rr = threadIdx.x >> 3, c4 = (threadIdx.x & 7) * 4;
#pragma unroll
    for (int i = 0; i < 4; i++) tile[rr][c4 + i] = src[(long)(t0 + rr) * DD + d0 + c4 + i];
    __syncthreads();
#pragma unroll
    for (int i = 0; i < 4; i++) dst[(long)(d0 + rr) * TT + t0 + c4 + i] = tile[c4 + i][rr];
}

// =====================================================================
// k_g128: 128x128 tile, K=256 as 8 iters of BK=32, double-buffered
// (2 x 16 KB LDS -> 4 blocks/CU), ONE barrier per iter, prefetch during
// compute. Coalesced bf16 repack epilogue (fused rowsum / relu*x).
// =====================================================================
enum { EPI_RELU_BF16 = 0, EPI_RELU_MULX_BF16 = 2 };

template <int EPI>
__global__ __launch_bounds__(256) void k_g128(const bf16* __restrict__ A,
                                              const bf16* __restrict__ B,
                                              bf16* __restrict__ C,
                                              const bf16* __restrict__ Xaux,
                                              float* __restrict__ Wsum) {
    __shared__ __align__(16) char smem[32768];  // 2 bufs x (A 8K | B 8K); repack overlays
    const int lda = DD, ldb = DD, ldc = NN;
    int bm = blockIdx.y * 128, bn = blockIdx.x * 128;
    int tid = threadIdx.x, w = tid >> 6, lane = tid & 63;
    int srow = lane >> 2, sch = lane & 3;  // staging: 16 rows x 4 chunks per inst

    floatx4 acc[4][4];
#pragma unroll
    for (int i = 0; i < 4; i++)
#pragma unroll
        for (int j = 0; j < 4; j++) acc[i][j] = (floatx4){0.f, 0.f, 0.f, 0.f};

#define STAGE32(buf, k0)                                                               \
    {                                                                                  \
        char* bb = smem + (buf)*16384;                                                 \
        _Pragma("unroll") for (int j = 0; j < 2; j++) {                                \
            int row = w * 32 + j * 16 + srow;                                          \
            gl16(A + (long)(bm + row) * lda + (k0) + sch * 8,                          \
                 bb + (w * 32 + j * 16) * 64 + lane * 16);                             \
            gl16(B + (long)(bn + row) * ldb + (k0) + sch * 8,                          \
                 bb + 8192 + (w * 32 + j * 16) * 64 + lane * 16);                      \
        }                                                                              \
    }

    int wm = (w >> 1) * 64, wn = (w & 1) * 64;
    int lm = lane & 15, kh = lane >> 4;

    STAGE32(0, 0);
#pragma unroll
    for (int it = 0; it < 8; it++) {
        __syncthreads();  // drains stage into buf it&1
        if (it < 7) STAGE32((it + 1) & 1, (it + 1) * 32);
        const char* Ab = smem + (it & 1) * 16384;
        const char* Bb = Ab + 8192;
        short8 af[4], bfr[4];
#pragma unroll
        for (int i = 0; i < 4; i++) af[i] = *(const short8*)(Ab + (wm + i * 16 + lm) * 64 + kh * 16);
#pragma unroll
        for (int j = 0; j < 4; j++) bfr[j] = *(const short8*)(Bb + (wn + j * 16 + lm) * 64 + kh * 16);
#pragma unroll
        for (int i = 0; i < 4; i++)
#pragma unroll
            for (int j = 0; j < 4; j++)
                acc[i][j] = __builtin_amdgcn_mfma_f32_16x16x32_bf16(af[i], bfr[j], acc[i][j], 0, 0, 0);
    }
#undef STAGE32

    // ---- LDS repack epilogue: two 64-row passes, coalesced 16B stores ----
    bf16* R = (bf16*)smem;  // [64][136]
#pragma unroll
    for (int p = 0; p < 2; p++) {
        __syncthreads();
        if ((w >> 1) == p) {
#pragma unroll
            for (int i = 0; i < 4; i++)
#pragma unroll
                for (int j = 0; j < 4; j++)
#pragma unroll
                    for (int r = 0; r < 4; r++) {
                        int rr = i * 16 + kh * 4 + r;
                        int cc = wn + j * 16 + lm;
                        R[rr * 136 + cc] = __float2bfloat16(fmaxf(acc[i][j][r], 0.f));
                    }
        }
        __syncthreads();
#pragma unroll
        for (int it2 = 0; it2 < 4; it2++) {
            int row_l = it2 * 16 + (tid >> 4);
            int c8 = (tid & 15) * 8;
            short8 vv = *(const short8*)(R + row_l * 136 + c8);
            int gm = bm + p * 64 + row_l;
            long off = (long)gm * ldc + bn + c8;
            if (EPI == EPI_RELU_BF16) {
                *(short8*)(C + off) = vv;
                float s = 0.f;
#pragma unroll
                for (int k = 0; k < 8; k++) s += bfu2f(vv[k]);
#pragma unroll
                for (int o = 8; o > 0; o >>= 1) s += __shfl_down(s, o, 16);
                if ((tid & 15) == 0) atomicAdd(&Wsum[gm], s);
            } else {
                short8 xx = *(const short8*)(Xaux + off);
                short8 oo;
#pragma unroll
                for (int k = 0; k < 8; k++) oo[k] = f2bfu(bfu2f(vv[k]) * fmaxf(bfu2f(xx[k]), 0.f));
                *(short8*)(C + off) = oo;
            }
        }
    }
}

// =====================================================================
// k_g64x128: 64x128 tile, BK=64 dbuf, optional split-K, f32 out, batched.
// =====================================================================
template <int KITERS, int KSPLIT>
__global__ __launch_bounds__(256) void k_g64x128(const bf16* __restrict__ A, int lda, long sA,
                                                 const bf16* __restrict__ B, int ldb, long sB,
                                                 float* __restrict__ C, int ldc, long sC) {
    __shared__ __align__(16) char smem[49152];  // 2 x (A 8K | B 16K)
    int z = blockIdx.z;
    int bz = z / KSPLIT, ks = z % KSPLIT;
    A += (long)bz * sA;
    B += (long)bz * sB;
    int kbase = ks * KITERS * 64;
    long cbase = (long)z * sC;
    int bm = blockIdx.y * 64, bn = blockIdx.x * 128;
    int tid = threadIdx.x, w = tid >> 6, lane = tid & 63;
    int lrow = lane >> 3, lph = lane & 7;
    int csw = lph ^ lrow;

    floatx4 acc[2][4];
#pragma unroll
    for (int i = 0; i < 2; i++)
#pragma unroll
        for (int j = 0; j < 4; j++) acc[i][j] = (floatx4){0.f, 0.f, 0.f, 0.f};

#define STAGE64128(buf, k0)                                                            \
    {                                                                                  \
        char* bb = smem + (buf)*24576;                                                 \
        _Pragma("unroll") for (int j = 0; j < 2; j++) {                                \
            int row = w * 16 + j * 8 + lrow;                                           \
            gl16(A + (long)(bm + row) * lda + (k0) + csw * 8,                          \
                 bb + (w * 16 + j * 8) * 128 + lane * 16);                             \
        }                                                                              \
        _Pragma("unroll") for (int j = 0; j < 4; j++) {                                \
            int row = w * 32 + j * 8 + lrow;                                           \
            gl16(B + (long)(bn + row) * ldb + (k0) + csw * 8,                          \
                 bb + 8192 + (w * 32 + j * 8) * 128 + lane * 16);                      \
        }                                                                              \
    }

    int wm = (w >> 1) * 32, wn = (w & 1) * 64;
    int lm = lane & 15, kh = lane >> 4;

    STAGE64128(0, kbase);
    for (int it = 0; it < KITERS; it++) {
        __syncthreads();
        if (it + 1 < KITERS) STAGE64128((it + 1) & 1, kbase + (it + 1) * 64);
        const char* Ab = smem + (it & 1) * 24576;
        const char* Bb = Ab + 8192;
#pragma unroll
        for (int ksu = 0; ksu < 2; ksu++) {
            int c = ksu * 4 + kh;
            short8 af[2], bfr[4];
#pragma unroll
            for (int i = 0; i < 2; i++) af[i] = frag64(Ab, wm + i * 16 + lm, c);
#pragma unroll
            for (int j = 0; j < 4; j++) bfr[j] = frag64(Bb, wn + j * 16 + lm, c);
#pragma unroll
            for (int i = 0; i < 2; i++)
#pragma unroll
                for (int j = 0; j < 4; j++)
                    acc[i][j] = __builtin_amdgcn_mfma_f32_16x16x32_bf16(af[i], bfr[j], acc[i][j], 0, 0, 0);
        }
    }
#undef STAGE64128

#pragma unroll
    for (int i = 0; i < 2; i++)
#pragma unroll
        for (int j = 0; j < 4; j++)
#pragma unroll
            for (int r = 0; r < 4; r++) {
                int gm = bm + wm + i * 16 + kh * 4 + r;
                int gn = bn + wn + j * 16 + lm;
                C[cbase + (long)gm * ldc + gn] = acc[i][j][r];
            }
}

// =====================================================================
// k_scores: 64x64 lower-tri tiles, split-K 4 (16 iters of BK=64 each),
// dbuf, f32 partials -> Gp[b][ks][256][256].
// =====================================================================
__global__ __launch_bounds__(256) void k_scores(const bf16* __restrict__ X,
                                                float* __restrict__ Gp) {
    __shared__ __align__(16) char smem[32768];  // 2 x (A 8K | B 8K)
    const int tri_i[10] = {0, 1, 1, 2, 2, 2, 3, 3, 3, 3};
    const int tri_j[10] = {0, 0, 1, 0, 1, 2, 0, 1, 2, 3};
    int z = blockIdx.z;
    int b = z >> 2, ks = z & 3;
    const bf16* A = X + (long)b * TT * NN;
    int kbase = ks * 1024;
    int bm = tri_i[blockIdx.x] * 64, bn = tri_j[blockIdx.x] * 64;
    int tid = threadIdx.x, w = tid >> 6, lane = tid & 63;
    int lrow = lane >> 3, lph = lane & 7;
    int csw = lph ^ lrow;

    floatx4 acc[2][2];
#pragma unroll
    for (int i = 0; i < 2; i++)
#pragma unroll
        for (int j = 0; j < 2; j++) acc[i][j] = (floatx4){0.f, 0.f, 0.f, 0.f};

#define STAGESC(buf, k0)                                                               \
    {                                                                                  \
        char* bb = smem + (buf)*16384;                                                 \
        _Pragma("unroll") for (int j = 0; j < 2; j++) {                                \
            int row = w * 16 + j * 8 + lrow;                                           \
            gl16(A + (long)(bm + row) * NN + (k0) + csw * 8,                           \
                 bb + (w * 16 + j * 8) * 128 + lane * 16);                             \
            gl16(A + (long)(bn + row) * NN + (k0) + csw * 8,                           \
                 bb + 8192 + (w * 16 + j * 8) * 128 + lane * 16);                      \
        }                                                                              \
    }

    int wm = (w >> 1) * 32, wn = (w & 1) * 32;
    int lm = lane & 15, kh = lane >> 4;

    STAGESC(0, kbase);
    for (int it = 0; it < 16; it++) {
        __syncthreads();
        if (it < 15) STAGESC((it + 1) & 1, kbase + (it + 1) * 64);
        const char* Ab = smem + (it & 1) * 16384;
        const char* Bb = Ab + 8192;
#pragma unroll
        for (int ksu = 0; ksu < 2; ksu++) {
            int c = ksu * 4 + kh;
            short8 af[2], bfr[2];
#pragma unroll
            for (int i = 0; i < 2; i++) af[i] = frag64(Ab, wm + i * 16 + lm, c);
#pragma unroll
            for (int j = 0; j < 2; j++) bfr[j] = frag64(Bb, wn + j * 16 + lm, c);
#pragma unroll
            for (int i = 0; i < 2; i++)
#pragma unroll
                for (int j = 0; j < 2; j++)
                    acc[i][j] = __builtin_amdgcn_mfma_f32_16x16x32_bf16(af[i], bfr[j], acc[i][j], 0, 0, 0);
        }
    }
#undef STAGESC

    float* Gb = Gp + ((long)b * 4 + ks) * 65536;
#pragma unroll
    for (int i = 0; i < 2; i++)
#pragma unroll
        for (int j = 0; j < 2; j++)
#pragma unroll
            for (int r = 0; r < 4; r++) {
                int gt = bm + wm + i * 16 + kh * 4 + r;
                int gs = bn + wn + j * 16 + lm;
                Gb[(long)gt * TT + gs] = acc[i][j][r];
            }
}

// ---------------- reduce 4 split-K score partials + causal decay mask -> G bf16 ----------------
__global__ __launch_bounds__(256) void k_reduce_mask(const float* __restrict__ Gp,
                                                     bf16* __restrict__ G) {
    int r = blockIdx.x;
    int b = r >> 8, t = r & 255;
    int s = threadIdx.x;
    float o = 0.f;
    if (s < t) {
        long base = ((long)b * 4) * 65536 + (long)t * 256 + s;
        float v = Gp[base] + Gp[base + 65536] + Gp[base + 2 * 65536] + Gp[base + 3 * 65536];
        o = v * exp2f((float)(t - s) * LOG2_DECAY);
    }
    G[(long)r * 256 + s] = __float2bfloat16(o);
}

// ---------------- scalar normalizer recurrence ----------------
__global__ __launch_bounds__(256) void k_scalar_scan(const float* __restrict__ Wsum,
                                                     float* __restrict__ invS) {
    __shared__ float sw[BB * TT];
    for (int i = threadIdx.x; i < BB * TT; i += 256) sw[i] = Wsum[i];
    __syncthreads();
    int b = threadIdx.x;
    if (b < BB) {
        float sig = 0.f;
        for (int t = 0; t < TT; t++) {
            float S = DECAY * sig + sw[b * TT + t];
            float inv = 1.f / (S + EPS);
            invS[b * TT + t] = inv;
            sig = S * inv;
        }
    }
}

// ---------------- column scan, 1 column/thread, 4-deep load prefetch ----------------
__global__ __launch_bounds__(256) void k_colscan(bf16* __restrict__ W,
                                                 const float* __restrict__ invS) {
    __shared__ float sv[TT];
    int b = blockIdx.y;
    sv[threadIdx.x] = invS[b * TT + threadIdx.x];
    __syncthreads();
    int n = blockIdx.x * 256 + threadIdx.x;
    bf16* p = W + (long)b * TT * NN + n;
    float x = 0.f;
    for (int t = 0; t < TT; t += 4) {
        short w0 = *(const short*)(p + (long)t * NN);
        short w1 = *(const short*)(p + (long)(t + 1) * NN);
        short w2 = *(const short*)(p + (long)(t + 2) * NN);
        short w3 = *(const short*)(p + (long)(t + 3) * NN);
        x = (DECAY * x + bfu2f(w0)) * sv[t];
        *(short*)(p + (long)t * NN) = f2bfu(x);
        x = (DECAY * x + bfu2f(w1)) * sv[t + 1];
        *(short*)(p + (long)(t + 1) * NN) = f2bfu(x);
        x = (DECAY * x + bfu2f(w2)) * sv[t + 2];
        *(short*)(p + (long)(t + 2) * NN) = f2bfu(x);
        x = (DECAY * x + bfu2f(w3)) * sv[t + 3];
        *(short*)(p + (long)(t + 3) * NN) = f2bfu(x);
    }
}

// ---------------- row layernorm Astar (fp32) -> ALN bf16 ----------------
__global__ __launch_bounds__(256) void k_ln_rows(const float* __restrict__ Z,
                                                 bf16* __restrict__ O) {
    __shared__ float s4[4];
    long r = blockIdx.x;
    int d = threadIdx.x;
    float z = Z[r * DD + d];
    float m = blk_sum_256(z, s4) * (1.0f / DD);
    float zc = z - m;
    float var = blk_sum_256(zc * zc, s4) * (1.0f / (DD - 1));
    O[r * DD + d] = __float2bfloat16(zc / (sqrtf(fmaxf(var, 0.f)) + EPS));
}

// ---------------- sum 4 split-K Z partials + layernorm -> output ----------------
__global__ __launch_bounds__(256) void k_final_ln(const float* __restrict__ Zp,
                                                  void* __restrict__ out,
                                                  const int* __restrict__ flag) {
    __shared__ float s4[4];
    long r = blockIdx.x;
    int d = threadIdx.x;
    const long SL = (long)8192 * 256;
    long o = r * DD + d;
    float z = Zp[o] + Zp[o + SL] + Zp[o + 2 * SL] + Zp[o + 3 * SL];
    float m = blk_sum_256(z, s4) * (1.0f / DD);
    float zc = z - m;
    float var = blk_sum_256(zc * zc, s4) * (1.0f / (DD - 1));
    float v = zc / (sqrtf(fmaxf(var, 0.f)) + EPS);
    if (flag[0]) ((bf16*)out)[o] = __float2bfloat16(v);
    else ((float*)out)[o] = v;
}

extern "C" void kernel_launch(void* const* d_in, const int* in_sizes, int n_in,
                              void* d_out, int out_size, void* d_ws, size_t ws_size,
                              hipStream_t stream) {
    const int* idx = (const int*)d_in[0];
    const void* emb = d_in[1];
    const void* E = d_in[2];
    const void* Dx = d_in[3];
    const void* Dy = d_in[4];

    // ---- workspace carve (bytes) ----
    char* base = (char*)d_ws;
    size_t off = 0;
    int* flag = (int*)base; off += 1024;
    bf16* Dxb = (bf16*)(base + off); off += (size_t)NN * DD * 2;
    bf16* Dyb = (bf16*)(base + off); off += (size_t)NN * DD * 2;
    bf16* Eb  = (bf16*)(base + off); off += (size_t)DD * NN * 2;
    bf16* Vpb = (bf16*)(base + off); off += (size_t)BB * TT * DD * 2;
    bf16* Ub  = (bf16*)(base + off); off += (size_t)BB * TT * DD * 2;
    bf16* Ut  = (bf16*)(base + off); off += (size_t)BB * TT * DD * 2;
    float* Wsum = (float*)(base + off); off += (size_t)BB * TT * 4;
    float* invS = (float*)(base + off); off += (size_t)BB * TT * 4;
    bf16* ALNb = (bf16*)(base + off); off += (size_t)BB * TT * DD * 2;
    bf16* G = (bf16*)(base + off); off += (size_t)BB * TT * TT * 2;        // 4MB
    float* Gp = (float*)(base + off); off += (size_t)4 * BB * TT * TT * 4; // 33.5MB (scores/Z partials)
    float* Zp = Gp;
    float* Astar = (float*)(base + off); off += (size_t)BB * TT * DD * 4;  // 8.4MB
    bf16* Xb = (bf16*)(base + off); off += (size_t)BB * TT * NN * 2;       // 67MB

    const int M = BB * TT;  // 8192

    k_detect<<<1, 256, 0, stream>>>((const unsigned short*)emb, flag);
    k_convert3<<<3 * NN * DD / 8 / 256, 256, 0, stream>>>(Dx, Dy, E, Dxb, Dyb, Eb, flag);
    k_gather_ln<<<M, 256, 0, stream>>>(emb, idx, Vpb, Ub, flag);
    k_transpose<<<dim3(8, 8, BB), 256, 0, stream>>>(Ub, Ut);

    hipMemsetAsync(Wsum, 0, (size_t)M * 4, stream);

    // W = relu(Vp @ Dx^T) -> Xb (bf16), rowsums fused via atomics
    k_g128<EPI_RELU_BF16><<<dim3(NN / 128, M / 128, 1), 256, 0, stream>>>(
        Vpb, Dxb, Xb, nullptr, Wsum);

    k_scalar_scan<<<1, 256, 0, stream>>>(Wsum, invS);
    k_colscan<<<dim3(NN / 256, BB, 1), 256, 0, stream>>>(Xb, invS);

    // scores: lower-tri 64x64 tiles, split-K 4 -> f32 partials (1280 blocks)
    k_scores<<<dim3(10, 1, BB * 4), 256, 0, stream>>>(Xb, Gp);
    k_reduce_mask<<<M, 256, 0, stream>>>(Gp, G);

    // a* = Gm @ U (NT with Ut), batched, whole-K=256 -> f32 Astar
    k_g64x128<4, 1><<<dim3(DD / 128, TT / 64, BB), 256, 0, stream>>>(
        G, TT, (long)TT * TT, Ut, TT, (long)DD * TT, Astar, DD, (long)TT * DD);
    k_ln_rows<<<M, 256, 0, stream>>>(Astar, ALNb);

    // Y = relu(ALN @ Dy^T) * relu(X), in place over Xb
    k_g128<EPI_RELU_MULX_BF16><<<dim3(NN / 128, M / 128, 1), 256, 0, stream>>>(
        ALNb, Dyb, Xb, Xb, nullptr);

    // Z partials = Y @ E^T, split-K 4 (1024 blocks of 16 iters)
    k_g64x128<16, 4><<<dim3(DD / 128, M / 64, 4), 256, 0, stream>>>(
        Xb, NN, 0, Eb, NN, 0, Zp, DD, (long)M * DD);

    k_final_ln<<<M, 256, 0, stream>>>(Zp, d_out, flag);
}